// Round 6
// baseline (1446.925 us; speedup 1.0000x reference)
//
#include <hip/hip_runtime.h>
#include <stdint.h>

// Problem constants
#define B_ 2
#define N_ 25
#define S_ 4096
#define I_ 63
#define W_ 256
#define D_ 8
#define Z_ 16

typedef float f32x4 __attribute__((ext_vector_type(4)));
typedef __bf16 bf16x8 __attribute__((ext_vector_type(8)));

// ---- bf16 split helpers (RNE) ----
__device__ __forceinline__ unsigned short f2bf(float x) {
  unsigned int u = __float_as_uint(x);
  unsigned int r = (u + 0x7fffu + ((u >> 16) & 1u)) >> 16;
  return (unsigned short)r;
}
__device__ __forceinline__ float bf2f(unsigned short h) {
  return __uint_as_float(((unsigned int)h) << 16);
}

// =====================================================================
// Prep: transpose [K][V] -> [V][Kp] (k-contiguous rows), split fp32 into
// bf16 hi/lo. in: [nmat][K][V]; out_hi/out_lo: [nmat][V][Kp].
// =====================================================================
__global__ void prep_tr(const float* __restrict__ in,
                        unsigned short* __restrict__ oh,
                        unsigned short* __restrict__ ol,
                        int K, int V, int Kp, int tiles_k, int tiles_v) {
  __shared__ float tile[64][65];
  int tpm = tiles_k * tiles_v;
  int m  = blockIdx.x / tpm;
  int tt = blockIdx.x - m * tpm;
  int tk = tt / tiles_v, tv = tt - tk * tiles_v;
  int k0 = tk * 64, v0 = tv * 64;
  const float* src = in + (size_t)m * K * V;
  int c  = threadIdx.x & 63;
  int r0 = threadIdx.x >> 6;
#pragma unroll
  for (int i = 0; i < 16; ++i) {
    int r = i * 4 + r0;
    int k = k0 + r, v = v0 + c;
    tile[r][c] = (k < K && v < V) ? src[(size_t)k * V + v] : 0.0f;
  }
  __syncthreads();
  unsigned short* dh = oh + (size_t)m * V * Kp;
  unsigned short* dl = ol + (size_t)m * V * Kp;
#pragma unroll
  for (int i = 0; i < 16; ++i) {
    int r = i * 4 + r0;
    int v = v0 + r, k = k0 + c;
    if (v < V && k < Kp) {
      float val = tile[c][r];
      unsigned short hi = f2bf(val);
      unsigned short lo = f2bf(val - bf2f(hi));
      dh[(size_t)v * Kp + k] = hi;
      dl[(size_t)v * Kp + k] = lo;
    }
  }
}

// =====================================================================
// Fused MLP main kernel, v4: round-2 geometry + m201-style raw-barrier
// counted-vmcnt pipeline (NO __syncthreads in the K-loop — __syncthreads
// forces a compiler vmcnt(0) drain, which nullified rounds 2-4).
// Grid: 1600 = 25 n x 64 token-tiles (128 tokens). Block 512 (8 waves),
// wave tile 64x64 (acc[4][4]).
// LDS 160 KB: Ah/Al [128][256] bf16 (2x64KB, XOR-swizzled) +
//             Bb0/Bb1 [256][32] bf16 (2x16KB ping-pong).
// Uniform phase stream across ALL layers: phase s stages phase s+1's
// chunk into the other buffer; s_waitcnt vmcnt(2) waits only the CURRENT
// phase's 2 loads (next phase's 2 remain in flight across both raw
// barriers). Last phase of each layer stages the NEXT layer's first
// chunk (layer 6 stages the whole 16KB Z-layer block). vmcnt(0) occurs
// exactly once, before the final Z-layer MFMAs.
// A swizzle: elem(tok,k) = tok*256 + (((k>>3) ^ (tok&31))<<3) + (k&7)
// B swizzle: elem(v,k)   = v*32   + (((k>>3) ^ ((v>>1)&3))<<3) + (k&7)
// =====================================================================
__device__ __forceinline__ void stage_B(const unsigned short* __restrict__ w,
                                        int rowlen, int kbase,
                                        unsigned short* Bb, int tid) {
  int wavebase = (tid >> 6) << 6;
#pragma unroll
  for (int p = 0; p < 2; ++p) {
    int t = tid + p * 512;          // 16B-block id, 0..1023 (16 KB)
    int v = t >> 2, blkp = t & 3;
    int blk = blkp ^ ((v >> 1) & 3);  // inverse-swizzled global source (G21)
    const unsigned short* g = w + (size_t)v * rowlen + kbase + blk * 8;
    unsigned short* ldsb = Bb + (size_t)(wavebase + p * 512) * 8; // wave-uniform
    __builtin_amdgcn_global_load_lds((const __attribute__((address_space(1))) void*)g,
                                     (__attribute__((address_space(3))) void*)ldsb,
                                     16, 0, 0);
  }
}

__global__ __launch_bounds__(512) void mlp_fused(
    const float* __restrict__ x, const float* __restrict__ b0,
    const float* __restrict__ bmid, const float* __restrict__ blast,
    const unsigned short* __restrict__ wt0h, const unsigned short* __restrict__ wt0l,
    const unsigned short* __restrict__ wtmh, const unsigned short* __restrict__ wtml,
    const unsigned short* __restrict__ wtlh, const unsigned short* __restrict__ wtll,
    float* __restrict__ out) {
  extern __shared__ unsigned short smem[];
  unsigned short* Ah  = smem;            // 32768 elems
  unsigned short* Al  = smem + 32768;    // 32768 elems
  unsigned short* Bb0 = smem + 65536;    // 8192 elems
  unsigned short* Bb1 = smem + 73728;    // 8192 elems

  const int tid  = threadIdx.x;
  const int lane = tid & 63;
  const int wave = tid >> 6;
  const int lrow = lane & 15;   // MFMA row/col-within-16
  const int lk   = lane >> 4;   // MFMA k-octet

  // XCD-chunked bijective swizzle (1600 = 8*200): co-resident blocks on an
  // XCD share n -> that n's ~1.7MB weight set stays L2-resident.
  const int bid = blockIdx.x;
  const int w   = (bid & 7) * 200 + (bid >> 3);
  const int n   = w >> 6;        // 0..24
  const int t   = w & 63;
  const int bb  = t >> 5;        // batch
  const int s0  = (t & 31) * 128;

  const int tg = wave >> 2;      // token group (0..1)
  const int vg = wave & 3;       // v group (0..3)

  // ---- prologue: stage layer-0 (hi, kc=0) into Bb0 (hidden under x-stage) ----
  stage_B(wt0h + (size_t)n * (W_ * 64), 64, 0, Bb0, tid);

  // ---- stage x (fp32 -> hi/lo bf16) into Ah/Al, k padded to 64 ----
  {
    const float* xp = x + (((size_t)bb * N_ + n) * S_ + s0) * I_;
#pragma unroll
    for (int i = 0; i < 16; ++i) {
      int e = i * 512 + tid;      // 0..8191
      int tok = e >> 6, k = e & 63;
      float val = (k < I_) ? xp[tok * I_ + k] : 0.0f;
      unsigned short hi = f2bf(val);
      unsigned short lo = f2bf(val - bf2f(hi));
      int off = tok * 256 + ((((k >> 3) ^ (tok & 31)) << 3) | (k & 7));
      Ah[off] = hi;
      Al[off] = lo;
    }
  }
  asm volatile("s_waitcnt lgkmcnt(0)" ::: "memory");
  __builtin_amdgcn_s_barrier();

  f32x4 acc[4][4];
  bf16x8 ahf[4], alf[4];

  // ---- layers 0..6 (input layer K=64(pad) + 6 mid layers K=256) ----
#pragma unroll 1
  for (int l = 0; l < 7; ++l) {
    const unsigned short *wh, *wl;
    const float* bias;
    int rowlen, nph;
    if (l == 0) {
      wh = wt0h + (size_t)n * (W_ * 64);
      wl = wt0l + (size_t)n * (W_ * 64);
      bias = b0 + n * W_;
      rowlen = 64; nph = 4;           // 2 kc x {hi,lo}
    } else {
      size_t o = ((size_t)(l - 1) * N_ + n) * ((size_t)W_ * W_);
      wh = wtmh + o;
      wl = wtml + o;
      bias = bmid + ((size_t)(l - 1) * N_ + n) * W_;
      rowlen = W_; nph = 16;          // 8 kc x {hi,lo}
    }
    // next layer's first (hi, kc=0) chunk pointer (mid layers only)
    const unsigned short* nwh = wtmh + ((size_t)l * N_ + n) * ((size_t)W_ * W_);

#pragma unroll
    for (int i = 0; i < 4; ++i)
#pragma unroll
      for (int j = 0; j < 4; ++j)
        acc[i][j] = (f32x4){0.f, 0.f, 0.f, 0.f};

#pragma unroll 1
    for (int s = 0; s < nph; ++s) {
      unsigned short* cur = (s & 1) ? Bb1 : Bb0;
      unsigned short* nxt = (s & 1) ? Bb0 : Bb1;

      // issue next phase's stage (2 global_load_lds per thread)
      if (s + 1 < nph) {
        stage_B(((s + 1) & 1) ? wl : wh, rowlen, ((s + 1) >> 1) * 32, nxt, tid);
      } else if (l < 6) {
        stage_B(nwh, W_, 0, nxt, tid);        // next layer (hi, kc=0) -> Bb0
      } else {
        // layer 6 last phase: stage the ENTIRE Z-layer 16KB into nxt (= Bb0).
        // Chunk c = kc*2+hl: [16 v][32 k] at c*512 shorts.
        const unsigned short* fh = wtlh + (size_t)n * (Z_ * W_);
        const unsigned short* fl = wtll + (size_t)n * (Z_ * W_);
        int wavebase = (tid >> 6) << 6;
#pragma unroll
        for (int p = 0; p < 2; ++p) {
          int idx = p * 512 + tid;        // 16B-block id 0..1023
          int c = idx >> 6;               // chunk 0..15
          int bq = idx & 63;
          int v = bq >> 2, blkp = bq & 3;
          int blk = blkp ^ ((v >> 1) & 3);
          int kc2 = c >> 1, hl = c & 1;
          const unsigned short* gsrc = (hl ? fl : fh) + (size_t)v * W_ + kc2 * 32 + blk * 8;
          unsigned short* ldsb = nxt + (size_t)(wavebase + p * 512) * 8;
          __builtin_amdgcn_global_load_lds((const __attribute__((address_space(1))) void*)gsrc,
                                           (__attribute__((address_space(3))) void*)ldsb,
                                           16, 0, 0);
        }
      }

      // counted wait: current phase's 2 loads done; next phase's stay in flight
      asm volatile("s_waitcnt vmcnt(2)" ::: "memory");
      __builtin_amdgcn_s_barrier();
      asm volatile("" ::: "memory");

      int kc = s >> 1;
      if ((s & 1) == 0) {  // hi phase: load A frags, terms ah*bh + al*bh
#pragma unroll
        for (int rt = 0; rt < 4; ++rt) {
          int tok = tg * 64 + rt * 16 + lrow;
          int off = tok * 256 + (((kc * 4 + lk) ^ (tok & 31)) << 3);
          ahf[rt] = *(const bf16x8*)(Ah + off);
          alf[rt] = *(const bf16x8*)(Al + off);
        }
        __builtin_amdgcn_s_setprio(1);
#pragma unroll
        for (int vt = 0; vt < 4; ++vt) {
          int v = vg * 64 + vt * 16 + lrow;
          bf16x8 bf = *(const bf16x8*)(cur + v * 32 + ((lk ^ ((v >> 1) & 3)) << 3));
#pragma unroll
          for (int rt = 0; rt < 4; ++rt)
            acc[rt][vt] = __builtin_amdgcn_mfma_f32_16x16x32_bf16(ahf[rt], bf, acc[rt][vt], 0, 0, 0);
#pragma unroll
          for (int rt = 0; rt < 4; ++rt)
            acc[rt][vt] = __builtin_amdgcn_mfma_f32_16x16x32_bf16(alf[rt], bf, acc[rt][vt], 0, 0, 0);
        }
        __builtin_amdgcn_s_setprio(0);
      } else {             // lo phase: reuse ahf, term ah*bl
        __builtin_amdgcn_s_setprio(1);
#pragma unroll
        for (int vt = 0; vt < 4; ++vt) {
          int v = vg * 64 + vt * 16 + lrow;
          bf16x8 bf = *(const bf16x8*)(cur + v * 32 + ((lk ^ ((v >> 1) & 3)) << 3));
#pragma unroll
          for (int rt = 0; rt < 4; ++rt)
            acc[rt][vt] = __builtin_amdgcn_mfma_f32_16x16x32_bf16(ahf[rt], bf, acc[rt][vt], 0, 0, 0);
        }
        __builtin_amdgcn_s_setprio(0);
      }
      asm volatile("" ::: "memory");
      __builtin_amdgcn_s_barrier();   // all waves done reading cur
    }

    // ---- epilogue: bias + ReLU + hi/lo split -> Ah/Al ----
#pragma unroll
    for (int vt = 0; vt < 4; ++vt) {
      int col = vg * 64 + vt * 16 + lrow;
      float bv = bias[col];
#pragma unroll
      for (int rt = 0; rt < 4; ++rt) {
        f32x4 cfr = acc[rt][vt];
#pragma unroll
        for (int r = 0; r < 4; ++r) {
          int tok = tg * 64 + rt * 16 + lk * 4 + r;  // C: row=(lane>>4)*4+reg
          float val = fmaxf(cfr[r] + bv, 0.0f);
          unsigned short hi = f2bf(val);
          unsigned short lo = f2bf(val - bf2f(hi));
          int off = tok * 256 + ((((col >> 3) ^ (tok & 31)) << 3) | (col & 7));
          Ah[off] = hi;
          Al[off] = lo;
        }
      }
    }
    asm volatile("s_waitcnt lgkmcnt(0)" ::: "memory");  // A-writes visible
    __builtin_amdgcn_s_barrier();
  }

  // ---- last layer: K=256 -> Z=16 (weights already staged into Bb0) ----
  {
    asm volatile("s_waitcnt vmcnt(0)" ::: "memory");   // final stage landed
    __builtin_amdgcn_s_barrier();

    f32x4 accL = (f32x4){0.f, 0.f, 0.f, 0.f};
    int v = lrow;
    int boff = v * 32 + ((lk ^ ((v >> 1) & 3)) << 3);
#pragma unroll
    for (int kc = 0; kc < 8; ++kc) {
      int tok = wave * 16 + lrow;
      int aoff = tok * 256 + (((kc * 4 + lk) ^ (tok & 31)) << 3);
      bf16x8 ahfL = *(const bf16x8*)(Ah + aoff);
      bf16x8 alfL = *(const bf16x8*)(Al + aoff);
      bf16x8 bh = *(const bf16x8*)(Bb0 + (kc * 2) * 512 + boff);
      bf16x8 bl = *(const bf16x8*)(Bb0 + (kc * 2 + 1) * 512 + boff);
      accL = __builtin_amdgcn_mfma_f32_16x16x32_bf16(ahfL, bh, accL, 0, 0, 0);
      accL = __builtin_amdgcn_mfma_f32_16x16x32_bf16(alfL, bh, accL, 0, 0, 0);
      accL = __builtin_amdgcn_mfma_f32_16x16x32_bf16(ahfL, bl, accL, 0, 0, 0);
    }
    float bv = blast[n * Z_ + lrow];
    float* op = out + (((size_t)bb * N_ + n) * S_ + s0) * Z_;
#pragma unroll
    for (int r = 0; r < 4; ++r) {
      int tok = wave * 16 + lk * 4 + r;
      op[(size_t)tok * Z_ + lrow] = accL[r] + bv;
    }
  }
}

// =====================================================================
// Fallback: pure-fp32 vector-ALU path, no workspace. Correct but slow.
// Fires only if ws_size/LDS opt-in fails.
// =====================================================================
__global__ __launch_bounds__(256) void mlp_fallback(
    const float* __restrict__ x, const float* __restrict__ W0,
    const float* __restrict__ b0, const float* __restrict__ Wmid,
    const float* __restrict__ bmid, const float* __restrict__ Wlast,
    const float* __restrict__ blast, float* __restrict__ out) {
  __shared__ float h[64][256];
  const int g  = blockIdx.x;
  const int n  = g >> 7;
  const int t  = g & 127;
  const int bb = t >> 6;
  const int s0 = (t & 63) * 64;
  const int v  = threadIdx.x;

  const float* xp = x + (((size_t)bb * N_ + n) * S_ + s0) * I_;
  float r[64];
  {
    const float* w = W0 + (size_t)n * I_ * W_;
    float bv = b0[n * W_ + v];
#pragma unroll 8
    for (int i = 0; i < 64; ++i) r[i] = bv;
    for (int k = 0; k < I_; ++k) {
      float wv = w[(size_t)k * W_ + v];
#pragma unroll
      for (int i = 0; i < 64; ++i) r[i] += xp[(size_t)i * I_ + k] * wv;
    }
#pragma unroll
    for (int i = 0; i < 64; ++i) h[i][v] = fmaxf(r[i], 0.f);
    __syncthreads();
  }
  for (int d = 0; d < D_ - 2; ++d) {
    const float* w = Wmid + ((size_t)d * N_ + n) * W_ * W_;
    float bv = bmid[((size_t)d * N_ + n) * W_ + v];
#pragma unroll 8
    for (int i = 0; i < 64; ++i) r[i] = bv;
    for (int k = 0; k < W_; ++k) {
      float wv = w[(size_t)k * W_ + v];
#pragma unroll
      for (int i = 0; i < 64; ++i) r[i] += h[i][k] * wv;
    }
    __syncthreads();
#pragma unroll
    for (int i = 0; i < 64; ++i) h[i][v] = fmaxf(r[i], 0.f);
    __syncthreads();
  }
  if (v < Z_) {
    const float* w = Wlast + (size_t)n * W_ * Z_;
    float bv = blast[n * Z_ + v];
#pragma unroll 8
    for (int i = 0; i < 64; ++i) r[i] = bv;
    for (int k = 0; k < W_; ++k) {
      float wv = w[(size_t)k * Z_ + v];
#pragma unroll
      for (int i = 0; i < 64; ++i) r[i] += h[i][k] * wv;
    }
    float* op = out + (((size_t)bb * N_ + n) * S_ + s0) * Z_;
#pragma unroll
    for (int i = 0; i < 64; ++i) op[(size_t)i * Z_ + v] = r[i];
  }
}

// =====================================================================
extern "C" void kernel_launch(void* const* d_in, const int* in_sizes, int n_in,
                              void* d_out, int out_size, void* d_ws, size_t ws_size,
                              hipStream_t stream) {
  const float* x     = (const float*)d_in[0];
  const float* W0    = (const float*)d_in[1];
  const float* b0    = (const float*)d_in[2];
  const float* Wmid  = (const float*)d_in[3];
  const float* bmid  = (const float*)d_in[4];
  const float* Wlast = (const float*)d_in[5];
  const float* blast = (const float*)d_in[6];
  float* out = (float*)d_out;
  (void)in_sizes; (void)n_in; (void)out_size;

  const size_t n_wt0 = (size_t)N_ * W_ * 64;                 // 409,600
  const size_t n_wtm = (size_t)(D_ - 2) * N_ * W_ * W_;      // 9,830,400
  const size_t n_wtl = (size_t)N_ * Z_ * W_;                 // 102,400
  const size_t need_bytes = 2 * (n_wt0 + n_wtm + n_wtl) * sizeof(unsigned short);

  bool use_main = (ws_size >= need_bytes);
  if (use_main) {
    hipError_t e = hipFuncSetAttribute((const void*)mlp_fused,
                                       hipFuncAttributeMaxDynamicSharedMemorySize,
                                       163840);
    if (e != hipSuccess) use_main = false;
  }

  if (use_main) {
    unsigned short* ws   = (unsigned short*)d_ws;
    unsigned short* wt0h = ws;
    unsigned short* wt0l = wt0h + n_wt0;
    unsigned short* wtmh = wt0l + n_wt0;
    unsigned short* wtml = wtmh + n_wtm;
    unsigned short* wtlh = wtml + n_wtm;
    unsigned short* wtll = wtlh + n_wtl;

    // weight prep every call (ws re-poisoned before every timed launch)
    prep_tr<<<25 * 4, 256, 0, stream>>>(W0, wt0h, wt0l, I_, W_, 64, 1, 4);
    prep_tr<<<150 * 16, 256, 0, stream>>>(Wmid, wtmh, wtml, W_, W_, W_, 4, 4);
    prep_tr<<<25 * 4, 256, 0, stream>>>(Wlast, wtlh, wtll, W_, Z_, W_, 4, 1);

    mlp_fused<<<1600, 512, 163840, stream>>>(x, b0, bmid, blast,
                                             wt0h, wt0l, wtmh, wtml, wtlh, wtll, out);
  } else {
    mlp_fallback<<<25 * 128, 256, 0, stream>>>(x, W0, b0, Wmid, bmid, Wlast, blast, out);
  }
}

// Round 7
// 760.733 us; speedup vs baseline: 1.9020x; 1.9020x over previous
//
#include <hip/hip_runtime.h>
#include <stdint.h>

// Problem constants
#define B_ 2
#define N_ 25
#define S_ 4096
#define I_ 63
#define W_ 256
#define D_ 8
#define Z_ 16

typedef float f32x4 __attribute__((ext_vector_type(4)));
typedef __bf16 bf16x8 __attribute__((ext_vector_type(8)));
typedef unsigned short u16x4 __attribute__((ext_vector_type(4)));

#define AS1 __attribute__((address_space(1)))
#define AS3 __attribute__((address_space(3)))

// ---- bf16 split helpers (RNE) ----
__device__ __forceinline__ unsigned short f2bf(float x) {
  unsigned int u = __float_as_uint(x);
  unsigned int r = (u + 0x7fffu + ((u >> 16) & 1u)) >> 16;
  return (unsigned short)r;
}
__device__ __forceinline__ float bf2f(unsigned short h) {
  return __uint_as_float(((unsigned int)h) << 16);
}

// =====================================================================
// Prep: transpose [K][V] -> [V][Kp] (k-contiguous rows), split fp32 into
// bf16 hi/lo. in: [nmat][K][V]; out_hi/out_lo: [nmat][V][Kp].
// =====================================================================
__global__ void prep_tr(const float* __restrict__ in,
                        unsigned short* __restrict__ oh,
                        unsigned short* __restrict__ ol,
                        int K, int V, int Kp, int tiles_k, int tiles_v) {
  __shared__ float tile[64][65];
  int tpm = tiles_k * tiles_v;
  int m  = blockIdx.x / tpm;
  int tt = blockIdx.x - m * tpm;
  int tk = tt / tiles_v, tv = tt - tk * tiles_v;
  int k0 = tk * 64, v0 = tv * 64;
  const float* src = in + (size_t)m * K * V;
  int c  = threadIdx.x & 63;
  int r0 = threadIdx.x >> 6;
#pragma unroll
  for (int i = 0; i < 16; ++i) {
    int r = i * 4 + r0;
    int k = k0 + r, v = v0 + c;
    tile[r][c] = (k < K && v < V) ? src[(size_t)k * V + v] : 0.0f;
  }
  __syncthreads();
  unsigned short* dh = oh + (size_t)m * V * Kp;
  unsigned short* dl = ol + (size_t)m * V * Kp;
#pragma unroll
  for (int i = 0; i < 16; ++i) {
    int r = i * 4 + r0;
    int v = v0 + r, k = k0 + c;
    if (v < V && k < Kp) {
      float val = tile[c][r];
      unsigned short hi = f2bf(val);
      unsigned short lo = f2bf(val - bf2f(hi));
      dh[(size_t)v * Kp + k] = hi;
      dl[(size_t)v * Kp + k] = lo;
    }
  }
}

// =====================================================================
// Fused MLP v5: barrier-free K-loop via per-wave private B staging.
// Grid: 1600 = 25 n x 64 token-tiles (128 tokens). Block 512 (8 waves).
// Wave w owns output cols [w*32, w*32+32) for ALL 128 tokens (acc[8][2]).
// LDS 160 KB: Ah/Al [128][256] bf16 (2x64KB, shared, XOR-swizzled) +
//   per-wave private B ping-pong: 8 waves x 2 bufs x 2KB = 32 KB.
// Each wave stages ONLY its own 32-col weight slice ([32c][32k] = 2KB
// per (kc,hi/lo) phase) via global_load_lds into its private buffers —
// WAR safety needs no barriers (private), vmcnt is per-wave. Waves run
// FREE within a layer (K-ring de-phased start kc = wave%nkc, so misses
// decorrelate); only 2 raw barriers per layer (A rewrite fence).
// MFMA operands SWAPPED (weights=arg0) so D reg-axis = cols: epilogue
// writes 4 cols per ds_write_b64, biases load as float4.
// A swizzle: elem(tok,k) = tok*256 + (((k>>3)^(tok&31))<<3) + (k&7)
// B chunk:   elem(c,k)   = c*32   + (((k>>3)^(c&3))<<3)     + (k&7)
// =====================================================================
__global__ __launch_bounds__(512) void mlp_fused(
    const float* __restrict__ x, const float* __restrict__ b0,
    const float* __restrict__ bmid, const float* __restrict__ blast,
    const unsigned short* __restrict__ wt0h, const unsigned short* __restrict__ wt0l,
    const unsigned short* __restrict__ wtmh, const unsigned short* __restrict__ wtml,
    const unsigned short* __restrict__ wtlh, const unsigned short* __restrict__ wtll,
    float* __restrict__ out) {
  extern __shared__ unsigned short smem[];
  unsigned short* Ah    = smem;            // 32768 shorts
  unsigned short* Al    = smem + 32768;    // 32768 shorts
  unsigned short* Bbase = smem + 65536;    // 16384 shorts (8 waves x 2048)

  const int tid  = threadIdx.x;
  const int lane = tid & 63;
  const int wave = tid >> 6;
  const int lrow = lane & 15;   // fragment row/col-within-16
  const int lk   = lane >> 4;   // k-octet / D-row quad
  unsigned short* Bw = Bbase + wave * 2048;   // two 1024-short bufs
  const int c0 = wave * 32;                   // this wave's col base

  // XCD-chunked bijective swizzle (1600 = 8*200): same-n blocks share L2.
  const int bid = blockIdx.x;
  const int w   = (bid & 7) * 200 + (bid >> 3);
  const int n   = w >> 6;
  const int t   = w & 63;
  const int bb  = t >> 5;
  const int s0  = (t & 31) * 128;

  // stage one 2KB chunk [32 cols][32 k] of one weight plane (per-wave)
  auto stage_w = [&](const unsigned short* wp, int rowlen, int kc,
                     unsigned short* dst) {
#pragma unroll
    for (int p = 0; p < 2; ++p) {
      int blk = p * 64 + lane;            // 16B-block 0..127
      int col = blk >> 2, octp = blk & 3;
      int oct = octp ^ (col & 3);         // inverse-swizzled source (G21)
      const unsigned short* g = wp + (size_t)(c0 + col) * rowlen + kc * 32 + oct * 8;
      __builtin_amdgcn_global_load_lds((const AS1 void*)g,
                                       (AS3 void*)(dst + p * 512), 16, 0, 0);
    }
  };

  // ---- prologue: per-wave stage of layer-0 (kc = wave&1, hi) -> buf0 ----
  stage_w(wt0h + (size_t)n * (W_ * 64), 64, wave & 1, Bw);

  // ---- stage x (fp32 -> hi/lo bf16) into Ah/Al, k padded to 64 ----
  {
    const float* xp = x + (((size_t)bb * N_ + n) * S_ + s0) * I_;
#pragma unroll
    for (int i = 0; i < 16; ++i) {
      int e = i * 512 + tid;
      int tok = e >> 6, k = e & 63;
      float val = (k < I_) ? xp[tok * I_ + k] : 0.0f;
      unsigned short hi = f2bf(val);
      unsigned short lo = f2bf(val - bf2f(hi));
      int off = tok * 256 + ((((k >> 3) ^ (tok & 31)) << 3) | (k & 7));
      Ah[off] = hi;
      Al[off] = lo;
    }
  }
  asm volatile("s_waitcnt lgkmcnt(0)" ::: "memory");
  __builtin_amdgcn_s_barrier();

  f32x4 acc[8][2];
  bf16x8 ahf[8];

  // ---- layers 0..6 ----
#pragma unroll 1
  for (int l = 0; l < 7; ++l) {
    const unsigned short *wh, *wl;
    const float* bias;
    int rowlen, nkc;
    if (l == 0) {
      wh = wt0h + (size_t)n * (W_ * 64);
      wl = wt0l + (size_t)n * (W_ * 64);
      bias = b0 + n * W_;
      rowlen = 64; nkc = 2;
    } else {
      size_t o = ((size_t)(l - 1) * N_ + n) * ((size_t)W_ * W_);
      wh = wtmh + o;
      wl = wtml + o;
      bias = bmid + ((size_t)(l - 1) * N_ + n) * W_;
      rowlen = W_; nkc = 8;
    }
    const unsigned short* nwh = wtmh + ((size_t)l * N_ + n) * ((size_t)W_ * W_);
    const int kmask = nkc - 1;
    const int r0 = wave & kmask;
    const int nph = nkc * 2;

    // bias (float4 x2) issued EARLY so it drains with the first vmcnt
    f32x4 bv0 = *(const f32x4*)(bias + c0 + lk * 4);
    f32x4 bv1 = *(const f32x4*)(bias + c0 + 16 + lk * 4);
    asm volatile("" ::: "memory");

#pragma unroll
    for (int i = 0; i < 8; ++i) {
      acc[i][0] = (f32x4){0.f, 0.f, 0.f, 0.f};
      acc[i][1] = (f32x4){0.f, 0.f, 0.f, 0.f};
    }

#pragma unroll 1
    for (int j = 0; j < nph; ++j) {
      const int hl = j & 1;
      const int kc = (r0 + (j >> 1)) & kmask;
      unsigned short* cur = Bw + (j & 1) * 1024;

      if (j + 1 < nph) {                       // prefetch next phase
        int jn = j + 1;
        stage_w((jn & 1) ? wl : wh, rowlen, (r0 + (jn >> 1)) & kmask,
                Bw + (jn & 1) * 1024);
        asm volatile("s_waitcnt vmcnt(2)" ::: "memory");
      } else if (l < 6) {                      // cross-layer prefetch -> buf0
        stage_w(nwh, W_, wave & 7, Bw);
        asm volatile("s_waitcnt vmcnt(2)" ::: "memory");
      } else {                                 // layer 6 tail: drain
        asm volatile("s_waitcnt vmcnt(0)" ::: "memory");
      }
      __builtin_amdgcn_sched_barrier(0);

      // weight fragments (arg0 side): lane row = col (lrow), octet = lk
      int cl0 = lrow, cl1 = 16 + lrow;
      bf16x8 bf0 = *(const bf16x8*)(cur + cl0 * 32 + ((lk ^ (cl0 & 3)) << 3));
      bf16x8 bf1 = *(const bf16x8*)(cur + cl1 * 32 + ((lk ^ (cl1 & 3)) << 3));

      if (hl == 0) {   // hi plane: ah*bh + al*bh ; ahf persists into lo phase
#pragma unroll
        for (int rt = 0; rt < 8; ++rt) {
          int tok = rt * 16 + lrow;
          int aoff = tok * 256 + (((kc * 4 + lk) ^ (tok & 31)) << 3);
          ahf[rt] = *(const bf16x8*)(Ah + aoff);
          bf16x8 alt = *(const bf16x8*)(Al + aoff);
          acc[rt][0] = __builtin_amdgcn_mfma_f32_16x16x32_bf16(bf0, ahf[rt], acc[rt][0], 0, 0, 0);
          acc[rt][1] = __builtin_amdgcn_mfma_f32_16x16x32_bf16(bf1, ahf[rt], acc[rt][1], 0, 0, 0);
          acc[rt][0] = __builtin_amdgcn_mfma_f32_16x16x32_bf16(bf0, alt, acc[rt][0], 0, 0, 0);
          acc[rt][1] = __builtin_amdgcn_mfma_f32_16x16x32_bf16(bf1, alt, acc[rt][1], 0, 0, 0);
        }
      } else {         // lo plane: ah*bl (reuse ahf)
#pragma unroll
        for (int rt = 0; rt < 8; ++rt) {
          acc[rt][0] = __builtin_amdgcn_mfma_f32_16x16x32_bf16(bf0, ahf[rt], acc[rt][0], 0, 0, 0);
          acc[rt][1] = __builtin_amdgcn_mfma_f32_16x16x32_bf16(bf1, ahf[rt], acc[rt][1], 0, 0, 0);
        }
      }
    }

    // ---- layer boundary: all waves done reading A ----
    asm volatile("s_waitcnt lgkmcnt(0)" ::: "memory");
    __builtin_amdgcn_s_barrier();

    // ---- epilogue: bias + ReLU + hi/lo split -> Ah/Al (b64 col-packed) ----
    // D layout (swapped operands): token = rt*16 + (lane&15),
    // col = c0 + vt*16 + lk*4 + r  (4 consecutive cols per f32x4).
#pragma unroll
    for (int rt = 0; rt < 8; ++rt) {
      int tok = rt * 16 + lrow;
#pragma unroll
      for (int vt = 0; vt < 2; ++vt) {
        f32x4 bv = vt ? bv1 : bv0;
        f32x4 cfr = acc[rt][vt];
        int colb = c0 + vt * 16 + lk * 4;     // 4-aligned, one octet
        int off = tok * 256 + ((((colb >> 3) ^ (tok & 31)) << 3) | (colb & 7));
        u16x4 h4, l4;
#pragma unroll
        for (int r = 0; r < 4; ++r) {
          float val = fmaxf(cfr[r] + bv[r], 0.0f);
          unsigned short hi = f2bf(val);
          h4[r] = hi;
          l4[r] = f2bf(val - bf2f(hi));
        }
        *(u16x4*)(Ah + off) = h4;
        *(u16x4*)(Al + off) = l4;
      }
    }
    asm volatile("s_waitcnt lgkmcnt(0)" ::: "memory");
    __builtin_amdgcn_s_barrier();
  }

  // ---- last layer: K=256 -> Z=16. Cooperative 16KB stage, then per-wave
  // barrier-free compute; out written as float4 (z quads). ----
  {
    const unsigned short* fh = wtlh + (size_t)n * (Z_ * W_);
    const unsigned short* fl = wtll + (size_t)n * (Z_ * W_);
    int wavebase = wave << 6;
#pragma unroll
    for (int p = 0; p < 2; ++p) {
      int idx = p * 512 + tid;          // 16B-block 0..1023
      int c = idx >> 6;                 // chunk (kc*2+hl) 0..15
      int bq = idx & 63;
      int v = bq >> 2, blkp = bq & 3;
      int blk = blkp ^ ((v >> 1) & 3);
      int kc2 = c >> 1, hl = c & 1;
      const unsigned short* g = (hl ? fl : fh) + (size_t)v * W_ + kc2 * 32 + blk * 8;
      unsigned short* ldsb = Bbase + (size_t)(wavebase + p * 512) * 8;
      __builtin_amdgcn_global_load_lds((const AS1 void*)g, (AS3 void*)ldsb, 16, 0, 0);
    }
    asm volatile("s_waitcnt vmcnt(0)" ::: "memory");
    __builtin_amdgcn_s_barrier();

    f32x4 accL = (f32x4){0.f, 0.f, 0.f, 0.f};
    int v = lrow;                                   // z index for arg0 frag
    int boff = v * 32 + ((lk ^ ((v >> 1) & 3)) << 3);
    int tok = wave * 16 + lrow;
#pragma unroll
    for (int kc = 0; kc < 8; ++kc) {
      int aoff = tok * 256 + (((kc * 4 + lk) ^ (tok & 31)) << 3);
      bf16x8 ah = *(const bf16x8*)(Ah + aoff);
      bf16x8 al = *(const bf16x8*)(Al + aoff);
      bf16x8 bh = *(const bf16x8*)(Bbase + (kc * 2) * 512 + boff);
      bf16x8 bl = *(const bf16x8*)(Bbase + (kc * 2 + 1) * 512 + boff);
      accL = __builtin_amdgcn_mfma_f32_16x16x32_bf16(bh, ah, accL, 0, 0, 0);
      accL = __builtin_amdgcn_mfma_f32_16x16x32_bf16(bh, al, accL, 0, 0, 0);
      accL = __builtin_amdgcn_mfma_f32_16x16x32_bf16(bl, ah, accL, 0, 0, 0);
    }
    f32x4 bvz = *(const f32x4*)(blast + n * Z_ + lk * 4);
    float* op = out + (((size_t)bb * N_ + n) * S_ + s0) * Z_;
    f32x4 o;
#pragma unroll
    for (int r = 0; r < 4; ++r) o[r] = accL[r] + bvz[r];
    *(f32x4*)(op + (size_t)tok * Z_ + lk * 4) = o;   // token = lane&15, z = lk*4+r
  }
}

// =====================================================================
// Fallback: pure-fp32 vector-ALU path, no workspace. Correct but slow.
// =====================================================================
__global__ __launch_bounds__(256) void mlp_fallback(
    const float* __restrict__ x, const float* __restrict__ W0,
    const float* __restrict__ b0, const float* __restrict__ Wmid,
    const float* __restrict__ bmid, const float* __restrict__ Wlast,
    const float* __restrict__ blast, float* __restrict__ out) {
  __shared__ float h[64][256];
  const int g  = blockIdx.x;
  const int n  = g >> 7;
  const int t  = g & 127;
  const int bb = t >> 6;
  const int s0 = (t & 63) * 64;
  const int v  = threadIdx.x;

  const float* xp = x + (((size_t)bb * N_ + n) * S_ + s0) * I_;
  float r[64];
  {
    const float* wp = W0 + (size_t)n * I_ * W_;
    float bv = b0[n * W_ + v];
#pragma unroll 8
    for (int i = 0; i < 64; ++i) r[i] = bv;
    for (int k = 0; k < I_; ++k) {
      float wv = wp[(size_t)k * W_ + v];
#pragma unroll
      for (int i = 0; i < 64; ++i) r[i] += xp[(size_t)i * I_ + k] * wv;
    }
#pragma unroll
    for (int i = 0; i < 64; ++i) h[i][v] = fmaxf(r[i], 0.f);
    __syncthreads();
  }
  for (int d = 0; d < D_ - 2; ++d) {
    const float* wp = Wmid + ((size_t)d * N_ + n) * W_ * W_;
    float bv = bmid[((size_t)d * N_ + n) * W_ + v];
#pragma unroll 8
    for (int i = 0; i < 64; ++i) r[i] = bv;
    for (int k = 0; k < W_; ++k) {
      float wv = wp[(size_t)k * W_ + v];
#pragma unroll
      for (int i = 0; i < 64; ++i) r[i] += h[i][k] * wv;
    }
    __syncthreads();
#pragma unroll
    for (int i = 0; i < 64; ++i) h[i][v] = fmaxf(r[i], 0.f);
    __syncthreads();
  }
  if (v < Z_) {
    const float* wp = Wlast + (size_t)n * W_ * Z_;
    float bv = blast[n * Z_ + v];
#pragma unroll 8
    for (int i = 0; i < 64; ++i) r[i] = bv;
    for (int k = 0; k < W_; ++k) {
      float wv = wp[(size_t)k * Z_ + v];
#pragma unroll
      for (int i = 0; i < 64; ++i) r[i] += h[i][k] * wv;
    }
    float* op = out + (((size_t)bb * N_ + n) * S_ + s0) * Z_;
#pragma unroll
    for (int i = 0; i < 64; ++i) op[(size_t)i * Z_ + v] = r[i];
  }
}

// =====================================================================
extern "C" void kernel_launch(void* const* d_in, const int* in_sizes, int n_in,
                              void* d_out, int out_size, void* d_ws, size_t ws_size,
                              hipStream_t stream) {
  const float* x     = (const float*)d_in[0];
  const float* W0    = (const float*)d_in[1];
  const float* b0    = (const float*)d_in[2];
  const float* Wmid  = (const float*)d_in[3];
  const float* bmid  = (const float*)d_in[4];
  const float* Wlast = (const float*)d_in[5];
  const float* blast = (const float*)d_in[6];
  float* out = (float*)d_out;
  (void)in_sizes; (void)n_in; (void)out_size;

  const size_t n_wt0 = (size_t)N_ * W_ * 64;                 // 409,600
  const size_t n_wtm = (size_t)(D_ - 2) * N_ * W_ * W_;      // 9,830,400
  const size_t n_wtl = (size_t)N_ * Z_ * W_;                 // 102,400
  const size_t need_bytes = 2 * (n_wt0 + n_wtm + n_wtl) * sizeof(unsigned short);

  bool use_main = (ws_size >= need_bytes);
  if (use_main) {
    hipError_t e = hipFuncSetAttribute((const void*)mlp_fused,
                                       hipFuncAttributeMaxDynamicSharedMemorySize,
                                       163840);
    if (e != hipSuccess) use_main = false;
  }

  if (use_main) {
    unsigned short* ws   = (unsigned short*)d_ws;
    unsigned short* wt0h = ws;
    unsigned short* wt0l = wt0h + n_wt0;
    unsigned short* wtmh = wt0l + n_wt0;
    unsigned short* wtml = wtmh + n_wtm;
    unsigned short* wtlh = wtml + n_wtm;
    unsigned short* wtll = wtlh + n_wtl;

    prep_tr<<<25 * 4, 256, 0, stream>>>(W0, wt0h, wt0l, I_, W_, 64, 1, 4);
    prep_tr<<<150 * 16, 256, 0, stream>>>(Wmid, wtmh, wtml, W_, W_, W_, 4, 4);
    prep_tr<<<25 * 4, 256, 0, stream>>>(Wlast, wtlh, wtll, W_, Z_, W_, 4, 1);

    mlp_fused<<<1600, 512, 163840, stream>>>(x, b0, bmid, blast,
                                             wt0h, wt0l, wtmh, wtml, wtlh, wtll, out);
  } else {
    mlp_fallback<<<25 * 128, 256, 0, stream>>>(x, W0, b0, Wmid, bmid, Wlast, blast, out);
  }
}